// Round 3
// baseline (4965.583 us; speedup 1.0000x reference)
//
#include <hip/hip_runtime.h>
#include <math.h>

constexpr int TVL = 7500;   // T*V
constexpr int CIN = 256;
constexpr int CO  = 256;
constexpr int KO  = 768;    // K * C_OUT
constexpr int KK3 = 2304;   // C_OUT * TK (reordered k' = dt*256 + c)
#define BNEPS 1e-5f

typedef __attribute__((ext_vector_type(8))) short short8;   // 8 bf16 = 4 VGPRs
typedef __attribute__((ext_vector_type(4))) float f32x4;
typedef unsigned short ushortT;

// RNE float->bf16 (raw u16), and back
static __device__ __forceinline__ ushortT f2bf(float v) {
    unsigned x = __float_as_uint(v);
    unsigned r = (x + 0x7fffu + ((x >> 16) & 1u)) >> 16;
    return (ushortT)r;
}
static __device__ __forceinline__ float bf2f(ushortT u) {
    return __uint_as_float((unsigned)u << 16);
}

// ---------------------------------------------------------------------------
// Split weights: conv_w [768x256] -> hi/lo bf16, same layout.
// ---------------------------------------------------------------------------
__global__ void ksplit_w1(const float* __restrict__ w,
                          ushortT* __restrict__ dH, ushortT* __restrict__ dL)
{
    int i = blockIdx.x * 256 + threadIdx.x;
    if (i < KO * CIN) {
        float v = w[i];
        ushortT h = f2bf(v);
        dH[i] = h;
        dL[i] = f2bf(v - bf2f(h));
    }
}

// tconv_w [256][256][9] -> reordered [o][k'=dt*256+c] hi/lo bf16
__global__ void ksplit_w3(const float* __restrict__ w,
                          ushortT* __restrict__ dH, ushortT* __restrict__ dL)
{
    int i = blockIdx.x * 256 + threadIdx.x;
    if (i < CO * KK3) {
        int o = i / KK3, rem = i - o * KK3;
        int c = rem / 9, dt = rem - c * 9;
        float v = w[i];
        ushortT h = f2bf(v);
        int j = o * KK3 + dt * 256 + c;
        dH[j] = h;
        dL[j] = f2bf(v - bf2f(h));
    }
}

// ---------------------------------------------------------------------------
// Transpose+split: src [256][7500] f32 (per image z) -> dst [7500][256] bf16 hi/lo
// ---------------------------------------------------------------------------
__global__ __launch_bounds__(256) void ktrans_split(
    const float* __restrict__ src, ushortT* __restrict__ dH, ushortT* __restrict__ dL)
{
    __shared__ float tile[32][33];
    const int z = blockIdx.z;
    src += (size_t)z * CO * TVL;
    dH  += (size_t)z * TVL * 256;
    dL  += (size_t)z * TVL * 256;
    const int tx = threadIdx.x & 31, ty = threadIdx.x >> 5;
    const int wBase = blockIdx.x * 32, cBase = blockIdx.y * 32;
    #pragma unroll
    for (int i = 0; i < 4; ++i) {
        int r = ty + i * 8;
        int w = wBase + tx;
        tile[r][tx] = (w < TVL) ? src[(size_t)(cBase + r) * TVL + w] : 0.f;
    }
    __syncthreads();
    #pragma unroll
    for (int i = 0; i < 4; ++i) {
        int wr = ty + i * 8;
        int w = wBase + wr;
        if (w < TVL) {
            float v = tile[tx][wr];
            ushortT hi = f2bf(v);
            ushortT lo = f2bf(v - bf2f(hi));
            dH[(size_t)w * 256 + cBase + tx] = hi;
            dL[(size_t)w * 256 + cBase + tx] = lo;
        }
    }
}

// ---------------------------------------------------------------------------
// Kernel 1 (MFMA): out1[ng][o][col] = sum_c W[o][c]*x[ng][c][col] + b[o]
// Block tile 256(M) x 128(N), BK=32. 4 waves, wave-tile 128x64.
// ---------------------------------------------------------------------------
__global__ __launch_bounds__(256, 2) void k1_mfma(
    const ushortT* __restrict__ Wh, const ushortT* __restrict__ Wl,
    const ushortT* __restrict__ Xh, const ushortT* __restrict__ Xl,
    const float* __restrict__ bias, float* __restrict__ out1)
{
    __shared__ short Ah[256][40], Al[256][40], Bh[128][40], Bl[128][40];
    const int tid = threadIdx.x;
    const int ng = blockIdx.z;
    const int rowBase = blockIdx.y * 256;
    const int colBase = blockIdx.x * 128;
    const ushortT* XhN = Xh + (size_t)ng * TVL * 256;
    const ushortT* XlN = Xl + (size_t)ng * TVL * 256;

    f32x4 acc[8][4];
    #pragma unroll
    for (int a = 0; a < 8; ++a)
        #pragma unroll
        for (int b = 0; b < 4; ++b) acc[a][b] = (f32x4){0.f, 0.f, 0.f, 0.f};

    const int aRow = tid >> 2;          // 0..63
    const int kq4  = (tid & 3) << 3;    // {0,8,16,24} shorts
    const int wv = tid >> 6, lane = tid & 63;
    const int wy = wv >> 1, wx = wv & 1;
    const int q = lane >> 4, l15 = lane & 15;

    #pragma unroll 1
    for (int kk = 0; kk < CIN; kk += 32) {
        #pragma unroll
        for (int i = 0; i < 4; ++i) {
            const int r = aRow + i * 64;
            const size_t go = (size_t)(rowBase + r) * CIN + kk + kq4;
            *(short8*)&Ah[r][kq4] = *(const short8*)(Wh + go);
            *(short8*)&Al[r][kq4] = *(const short8*)(Wl + go);
        }
        #pragma unroll
        for (int i = 0; i < 2; ++i) {
            const int r = aRow + i * 64;     // 0..127
            const int bcol = colBase + r;
            short8 vh{}, vl{};
            if (bcol < TVL) {
                const size_t go = (size_t)bcol * 256 + kk + kq4;
                vh = *(const short8*)(XhN + go);
                vl = *(const short8*)(XlN + go);
            }
            *(short8*)&Bh[r][kq4] = vh;
            *(short8*)&Bl[r][kq4] = vl;
        }
        __syncthreads();

        short8 bh[4], bl[4];
        #pragma unroll
        for (int ni = 0; ni < 4; ++ni) {
            bh[ni] = *(const short8*)&Bh[wx * 64 + ni * 16 + l15][q * 8];
            bl[ni] = *(const short8*)&Bl[wx * 64 + ni * 16 + l15][q * 8];
        }
        #pragma unroll 4
        for (int mi = 0; mi < 8; ++mi) {
            const short8 ah = *(const short8*)&Ah[wy * 128 + mi * 16 + l15][q * 8];
            const short8 al = *(const short8*)&Al[wy * 128 + mi * 16 + l15][q * 8];
            #pragma unroll
            for (int ni = 0; ni < 4; ++ni) {
                acc[mi][ni] = __builtin_amdgcn_mfma_f32_16x16x32_bf16(ah, bh[ni], acc[mi][ni], 0, 0, 0);
                acc[mi][ni] = __builtin_amdgcn_mfma_f32_16x16x32_bf16(ah, bl[ni], acc[mi][ni], 0, 0, 0);
                acc[mi][ni] = __builtin_amdgcn_mfma_f32_16x16x32_bf16(al, bh[ni], acc[mi][ni], 0, 0, 0);
            }
        }
        __syncthreads();
    }

    float* out1n = out1 + (size_t)ng * KO * TVL;
    #pragma unroll
    for (int mi = 0; mi < 8; ++mi)
        #pragma unroll
        for (int rr = 0; rr < 4; ++rr) {
            const int row = rowBase + wy * 128 + mi * 16 + q * 4 + rr;
            const float bv = bias[row];
            #pragma unroll
            for (int ni = 0; ni < 4; ++ni) {
                const int col = colBase + wx * 64 + ni * 16 + l15;
                if (col < TVL)
                    out1n[(size_t)row * TVL + col] = acc[mi][ni][rr] + bv;
            }
        }
}

// ---------------------------------------------------------------------------
// Kernel 2: spatial graph contraction + BN1 + ReLU + split + transpose.
// Block = (ngL, t2); thread = c. Writes Hh/Hl[(n0+ngL)][col][c] directly.
// ---------------------------------------------------------------------------
__global__ __launch_bounds__(256) void k2_sgc(
    const float* __restrict__ out1, const float* __restrict__ A,
    const float* __restrict__ Mm, const float* __restrict__ g1,
    const float* __restrict__ b1, const float* __restrict__ m1,
    const float* __restrict__ v1,
    ushortT* __restrict__ Hh, ushortT* __restrict__ Hl, int n0)
{
    __shared__ __align__(16) float AMs[3 * 25 * 28];
    const int tid = threadIdx.x;
    for (int i = tid; i < 1875; i += 256)
        AMs[(i / 25) * 28 + (i % 25)] = A[i] * Mm[i];
    __syncthreads();

    const int bid = blockIdx.x;
    const int t2  = bid % 150;
    const int ngL = bid / 150;
    const int c   = tid;
    const int t   = t2 * 2;

    const float* base = out1 + ((size_t)ngL * KO + c) * TVL + t * 25;
    float o0[25], o1[25];
    #pragma unroll
    for (int w = 0; w < 25; ++w) { o0[w] = 0.f; o1[w] = 0.f; }

    for (int k = 0; k < 3; ++k) {
        const float* yp = base + (size_t)k * CO * TVL;
        float y0[25], y1[25];
        #pragma unroll
        for (int v = 0; v < 25; ++v) { y0[v] = yp[v]; y1[v] = yp[25 + v]; }
        const float* amk = &AMs[k * 700];
        for (int v = 0; v < 25; ++v) {
            const float* am = amk + v * 28;
            const float ya = y0[v], yb = y1[v];
            #pragma unroll
            for (int w = 0; w < 25; ++w) {
                const float a = am[w];
                o0[w] += ya * a;
                o1[w] += yb * a;
            }
        }
    }

    const float sc = g1[c] / sqrtf(v1[c] + BNEPS);
    const float bi = b1[c] - m1[c] * sc;
    const size_t nb = (size_t)(n0 + ngL) * TVL * 256;
    #pragma unroll
    for (int w = 0; w < 25; ++w) {
        const float va = fmaxf(o0[w] * sc + bi, 0.f);
        const float vb = fmaxf(o1[w] * sc + bi, 0.f);
        const size_t i0 = nb + (size_t)(t * 25 + w) * 256 + c;
        const size_t i1 = nb + (size_t)(t * 25 + 25 + w) * 256 + c;
        ushortT h0 = f2bf(va), h1 = f2bf(vb);
        Hh[i0] = h0; Hl[i0] = f2bf(va - bf2f(h0));
        Hh[i1] = h1; Hl[i1] = f2bf(vb - bf2f(h1));
    }
}

// ---------------------------------------------------------------------------
// Kernel 3 (MFMA): temporal conv + BN2 + ReLU + residual.
// Block tile 256(M=all o) x 128(N), BK=32, z = image. Wave-tile 128x64.
// ---------------------------------------------------------------------------
__global__ __launch_bounds__(256, 2) void k3_mfma(
    const ushortT* __restrict__ Wh, const ushortT* __restrict__ Wl,
    const ushortT* __restrict__ Hh, const ushortT* __restrict__ Hl,
    const float* __restrict__ tb, const float* __restrict__ g2,
    const float* __restrict__ b2, const float* __restrict__ m2,
    const float* __restrict__ v2, const float* __restrict__ x,
    float* __restrict__ out)
{
    __shared__ short Ah[256][40], Al[256][40], Bh[128][40], Bl[128][40];
    const int tid = threadIdx.x;
    const int ng = blockIdx.z;
    const int colBase = blockIdx.x * 128;
    const ushortT* HhN = Hh + (size_t)ng * TVL * 256;
    const ushortT* HlN = Hl + (size_t)ng * TVL * 256;

    f32x4 acc[8][4];
    #pragma unroll
    for (int a = 0; a < 8; ++a)
        #pragma unroll
        for (int b = 0; b < 4; ++b) acc[a][b] = (f32x4){0.f, 0.f, 0.f, 0.f};

    const int aRow = tid >> 2;
    const int kq4  = (tid & 3) << 3;
    const int wv = tid >> 6, lane = tid & 63;
    const int wy = wv >> 1, wx = wv & 1;
    const int q = lane >> 4, l15 = lane & 15;

    #pragma unroll 1
    for (int kk = 0; kk < KK3; kk += 32) {
        const int dt = kk >> 8;
        const int c0 = kk & 255;
        const int shift = dt * 25 - 100;
        #pragma unroll
        for (int i = 0; i < 4; ++i) {
            const int r = aRow + i * 64;
            const size_t go = (size_t)r * KK3 + kk + kq4;
            *(short8*)&Ah[r][kq4] = *(const short8*)(Wh + go);
            *(short8*)&Al[r][kq4] = *(const short8*)(Wl + go);
        }
        #pragma unroll
        for (int i = 0; i < 2; ++i) {
            const int r = aRow + i * 64;
            const int bcol = colBase + r;
            const int gcol = bcol + shift;
            short8 vh{}, vl{};
            if (bcol < TVL && (unsigned)gcol < (unsigned)TVL) {
                const size_t go = (size_t)gcol * 256 + c0 + kq4;
                vh = *(const short8*)(HhN + go);
                vl = *(const short8*)(HlN + go);
            }
            *(short8*)&Bh[r][kq4] = vh;
            *(short8*)&Bl[r][kq4] = vl;
        }
        __syncthreads();

        short8 bh[4], bl[4];
        #pragma unroll
        for (int ni = 0; ni < 4; ++ni) {
            bh[ni] = *(const short8*)&Bh[wx * 64 + ni * 16 + l15][q * 8];
            bl[ni] = *(const short8*)&Bl[wx * 64 + ni * 16 + l15][q * 8];
        }
        #pragma unroll 4
        for (int mi = 0; mi < 8; ++mi) {
            const short8 ah = *(const short8*)&Ah[wy * 128 + mi * 16 + l15][q * 8];
            const short8 al = *(const short8*)&Al[wy * 128 + mi * 16 + l15][q * 8];
            #pragma unroll
            for (int ni = 0; ni < 4; ++ni) {
                acc[mi][ni] = __builtin_amdgcn_mfma_f32_16x16x32_bf16(ah, bh[ni], acc[mi][ni], 0, 0, 0);
                acc[mi][ni] = __builtin_amdgcn_mfma_f32_16x16x32_bf16(ah, bl[ni], acc[mi][ni], 0, 0, 0);
                acc[mi][ni] = __builtin_amdgcn_mfma_f32_16x16x32_bf16(al, bh[ni], acc[mi][ni], 0, 0, 0);
            }
        }
        __syncthreads();
    }

    const float* xn = x   + (size_t)ng * CO * TVL;
    float*       on = out + (size_t)ng * CO * TVL;
    #pragma unroll
    for (int mi = 0; mi < 8; ++mi)
        #pragma unroll
        for (int rr = 0; rr < 4; ++rr) {
            const int row = wy * 128 + mi * 16 + q * 4 + rr;
            const float sc = g2[row] / sqrtf(v2[row] + BNEPS);
            const float bb = (tb[row] - m2[row]) * sc + b2[row];
            #pragma unroll
            for (int ni = 0; ni < 4; ++ni) {
                const int col = colBase + wx * 64 + ni * 16 + l15;
                if (col < TVL) {
                    const size_t o = (size_t)row * TVL + col;
                    on[o] = fmaxf(acc[mi][ni][rr] * sc + bb, 0.f) + xn[o];
                }
            }
        }
}

// ---------------------------------------------------------------------------
extern "C" void kernel_launch(void* const* d_in, const int* in_sizes, int n_in,
                              void* d_out, int out_size, void* d_ws, size_t ws_size,
                              hipStream_t stream)
{
    const float* x  = (const float*)d_in[0];
    const float* A  = (const float*)d_in[1];
    const float* Mm = (const float*)d_in[3];
    const float* cw = (const float*)d_in[4];
    const float* cb = (const float*)d_in[5];
    const float* g1 = (const float*)d_in[6];
    const float* b1 = (const float*)d_in[7];
    const float* m1 = (const float*)d_in[8];
    const float* v1 = (const float*)d_in[9];
    const float* tw = (const float*)d_in[10];
    const float* tb = (const float*)d_in[11];
    const float* g2 = (const float*)d_in[12];
    const float* b2 = (const float*)d_in[13];
    const float* m2 = (const float*)d_in[14];
    const float* v2 = (const float*)d_in[15];
    float* out = (float*)d_out;

    // Workspace: [W1 hi/lo][W3 hi/lo][Hh][Hl (full 16)][out1][Xh][Xl (group)]
    ushortT* W1h = (ushortT*)d_ws;
    ushortT* W1l = W1h + (size_t)KO * CIN;
    ushortT* W3h = W1l + (size_t)KO * CIN;
    ushortT* W3l = W3h + (size_t)CO * KK3;
    ushortT* Hh  = W3l + (size_t)CO * KK3;
    ushortT* Hl  = Hh + (size_t)16 * TVL * 256;
    char* dyn = (char*)(Hl + (size_t)16 * TVL * 256);
    const size_t fixed = (size_t)(dyn - (char*)d_ws);
    const size_t avail = ws_size > fixed ? ws_size - fixed : 0;
    // per-n group: out1 f32 + xT hi/lo bf16
    const size_t perN = (size_t)KO * TVL * 4 + 2 * (size_t)TVL * 256 * 2;
    int g = 16;
    while (g > 1 && (size_t)g * perN > avail) g >>= 1;

    float*   out1 = (float*)dyn;
    ushortT* Xh   = (ushortT*)(out1 + (size_t)g * KO * TVL);
    ushortT* Xl   = Xh + (size_t)g * TVL * 256;

    hipLaunchKernelGGL(ksplit_w1, dim3((KO * CIN + 255) / 256), dim3(256), 0, stream, cw, W1h, W1l);
    hipLaunchKernelGGL(ksplit_w3, dim3((CO * KK3 + 255) / 256), dim3(256), 0, stream, tw, W3h, W3l);

    for (int n0 = 0; n0 < 16; n0 += g) {
        hipLaunchKernelGGL(ktrans_split, dim3(235, 8, g), dim3(256), 0, stream,
                           x + (size_t)n0 * CIN * TVL, Xh, Xl);
        hipLaunchKernelGGL(k1_mfma, dim3(59, 3, g), dim3(256), 0, stream,
                           W1h, W1l, Xh, Xl, cb, out1);
        hipLaunchKernelGGL(k2_sgc, dim3(g * 150), dim3(256), 0, stream,
                           out1, A, Mm, g1, b1, m1, v1, Hh, Hl, n0);
    }
    hipLaunchKernelGGL(k3_mfma, dim3(59, 1, 16), dim3(256), 0, stream,
                       W3h, W3l, Hh, Hl, tb, g2, b2, m2, v2, x, out);
}